// Round 19
// baseline (599.707 us; speedup 1.0000x reference)
//
#include <hip/hip_runtime.h>
#include <hip/hip_bf16.h>
#include <cstdint>
#include <cstddef>

typedef __attribute__((ext_vector_type(8))) short short8;
typedef __attribute__((ext_vector_type(4))) short short4_;
typedef __attribute__((ext_vector_type(4))) float floatx4;
typedef __attribute__((ext_vector_type(4))) unsigned short ushort4_;

#define MFMA16(a, b, c) __builtin_amdgcn_mfma_f32_16x16x32_bf16((a), (b), (c), 0, 0, 0)

__device__ __forceinline__ unsigned short f2bf(float f) {
  __hip_bfloat16 h = __float2bfloat16(f);
  return *reinterpret_cast<unsigned short*>(&h);
}

__device__ __forceinline__ float exp2_fast(float x) {   // bare v_exp_f32 (exp2)
  float r;
  asm("v_exp_f32 %0, %1" : "=v"(r) : "v"(x));
  return r;
}

__device__ __forceinline__ void gl_lds16(const void* g, void* lds) {
  __builtin_amdgcn_global_load_lds(
      (const __attribute__((address_space(1))) void*)g,
      (__attribute__((address_space(3))) void*)lds, 16, 0, 0);
}

// ---------------------------------------------------------------- fused cast kernel
__global__ void cast5_f32_bf16(const float* __restrict__ x, const float* __restrict__ wq,
                               const float* __restrict__ wk, const float* __restrict__ wv,
                               const float* __restrict__ wo,
                               __hip_bfloat16* __restrict__ xb, __hip_bfloat16* __restrict__ wqb,
                               __hip_bfloat16* __restrict__ wkb, __hip_bfloat16* __restrict__ wvb,
                               __hip_bfloat16* __restrict__ wob) {
  const int bid = blockIdx.x;
  const float* src;
  __hip_bfloat16* dst;
  int base;
  if (bid < 16384)      { src = x;  dst = xb;  base = bid; }
  else if (bid < 20480) { src = wq; dst = wqb; base = bid - 16384; }
  else if (bid < 24576) { src = wk; dst = wkb; base = bid - 20480; }
  else if (bid < 28672) { src = wv; dst = wvb; base = bid - 24576; }
  else                  { src = wo; dst = wob; base = bid - 28672; }
  const int i = base * 1024 + threadIdx.x * 4;
  const float4 v = *reinterpret_cast<const float4*>(src + i);
  ushort4_ o = { f2bf(v.x), f2bf(v.y), f2bf(v.z), f2bf(v.w) };
  *reinterpret_cast<ushort4_*>(dst + i) = o;
}

// ---------------------------------------------------------------- GEMM: 256x256, BK=64, 4-phase
// = round-17 gemm256q (best total) with setprio REMOVED (m190: setprio hurts lockstep
// GEMM by suppressing the co-resident wave's ds_read issue during MFMA).
template <int MODE>
__global__ __launch_bounds__(512, 2)
void gemm256q(const __hip_bfloat16* __restrict__ Ap, const __hip_bfloat16* __restrict__ Bp,
              const float* __restrict__ bias, void* __restrict__ Cout,
              int M, int N, int K) {
  __shared__ __align__(16) __hip_bfloat16 SA[2][256 * 64];
  __shared__ __align__(16) __hip_bfloat16 SB[2][256 * 64];

  const int tid = threadIdx.x;
  const int wid = tid >> 6, lane = tid & 63;
  const int wr = wid >> 2, wc = wid & 3;
  const int g = lane >> 4, c16 = lane & 15;

  const int nbn = N >> 8;
  const int cpx = gridDim.x >> 3;
  const int swzb = (blockIdx.x & 7) * cpx + (blockIdx.x >> 3);
  const int bm = swzb / nbn, bn = swzb % nbn;

  const int srow8 = lane >> 3;
  const int sc8 = lane & 7;
  const int sgcol = (sc8 ^ srow8) * 8;

  floatx4 acc[8][4] = {};
  short8 af[4], bf[4];

  auto stageA = [&](int p, int kt, int slot) {
    const int ck = p * 8 + wid;
    const int row = ck * 8 + srow8;
    gl_lds16(Ap + (size_t)(bm * 256 + row) * K + kt * 64 + sgcol, SA[slot] + ck * 512);
  };
  auto stageB = [&](int p, int kt, int slot) {
    const int ck = p * 8 + wid;
    const int row = ck * 8 + srow8;
    gl_lds16(Bp + (size_t)(bn * 256 + row) * K + kt * 64 + sgcol, SB[slot] + ck * 512);
  };
  auto readA = [&](int slot, int mh, int kk) {
    const __hip_bfloat16* sa = SA[slot];
#pragma unroll
    for (int mi = 0; mi < 4; ++mi)
      af[mi] = *reinterpret_cast<const short8*>(
          sa + (wr * 128 + (mh * 4 + mi) * 16 + c16) * 64 + (((kk * 4 + g) ^ (c16 & 7)) * 8));
  };
  auto readB = [&](int slot, int kk) {
    const __hip_bfloat16* sb = SB[slot];
#pragma unroll
    for (int n = 0; n < 4; ++n)
      bf[n] = *reinterpret_cast<const short8*>(
          sb + (wc * 64 + n * 16 + c16) * 64 + (((kk * 4 + g) ^ (c16 & 7)) * 8));
  };
  auto mfma_q = [&](int mh) {
#pragma unroll
    for (int mi = 0; mi < 4; ++mi)
#pragma unroll
      for (int n = 0; n < 4; ++n)
        acc[mh * 4 + mi][n] = MFMA16(af[mi], bf[n], acc[mh * 4 + mi][n]);
  };

  const int nkt = K >> 6;
#pragma unroll
  for (int p = 0; p < 4; ++p) { stageA(p, 0, 0); stageB(p, 0, 0); }
  asm volatile("s_waitcnt vmcnt(0)" ::: "memory");
  __builtin_amdgcn_s_barrier();

  for (int kt = 0; kt < nkt; ++kt) {
    const int s = kt & 1;
    const bool hn = (kt + 1 < nkt);
    // phase 0
    readA(s, 0, 0);
    readB(s, 0);
    if (hn) { stageA(0, kt + 1, s ^ 1); stageB(0, kt + 1, s ^ 1);
              stageA(1, kt + 1, s ^ 1); stageB(1, kt + 1, s ^ 1); }
    __builtin_amdgcn_s_barrier();
    mfma_q(0);
    __builtin_amdgcn_s_barrier();
    // phase 1
    readA(s, 1, 0);
    if (hn) { stageA(2, kt + 1, s ^ 1); stageB(2, kt + 1, s ^ 1);
              stageA(3, kt + 1, s ^ 1); stageB(3, kt + 1, s ^ 1); }
    __builtin_amdgcn_s_barrier();
    mfma_q(1);
    __builtin_amdgcn_s_barrier();
    // phase 2
    readA(s, 0, 1);
    readB(s, 1);
    __builtin_amdgcn_s_barrier();
    mfma_q(0);
    __builtin_amdgcn_s_barrier();
    // phase 3
    readA(s, 1, 1);
    __builtin_amdgcn_s_barrier();
    mfma_q(1);
    if (hn) asm volatile("s_waitcnt vmcnt(0)" ::: "memory");
    __builtin_amdgcn_s_barrier();
  }

#pragma unroll
  for (int n = 0; n < 4; ++n) {
    const int colg = bn * 256 + wc * 64 + n * 16 + c16;
    const float bv = bias[colg];
#pragma unroll
    for (int m = 0; m < 8; ++m) {
      const int rowg = bm * 256 + wr * 128 + m * 16 + g * 4;
      if (MODE == 0) {
        __hip_bfloat16* C = (__hip_bfloat16*)Cout;
#pragma unroll
        for (int j = 0; j < 4; ++j)
          C[(size_t)(rowg + j) * N + colg] = __float2bfloat16(acc[m][n][j] + bv);
      } else if (MODE == 1) {
        __hip_bfloat16* C = (__hip_bfloat16*)Cout;
        const int bb = rowg >> 11, t0 = rowg & 2047;
        ushort4_ pk = { f2bf(acc[m][n][0] + bv), f2bf(acc[m][n][1] + bv),
                        f2bf(acc[m][n][2] + bv), f2bf(acc[m][n][3] + bv) };
        *reinterpret_cast<ushort4_*>(C + ((size_t)bb * 2048 + colg) * 2048 + t0) = pk;
      } else {
        float* C = (float*)Cout;
#pragma unroll
        for (int j = 0; j < 4; ++j)
          C[(size_t)(rowg + j) * N + colg] = acc[m][n][j] + bv;
      }
    }
  }
}

// ---------------------------------------------------------------- flash attention v13 (causal)
// 2-wave blocks (QBLK=64), 4 independent blocks/CU (36 KB LDS, 4 desynced barrier groups)
// — the only mechanism that produced pipe overlap so far is independent blocks; this
// doubles them. Per-wave code identical to proven v12 (32 q-rows/wave, swapped-operand
// softmax, exp2-domain pre-scaled Q, defer-max, mask-path split, XOR LDS).
__global__ __launch_bounds__(128, 2)
void attn_fwd13(const __hip_bfloat16* __restrict__ Q, const __hip_bfloat16* __restrict__ K,
                const __hip_bfloat16* __restrict__ Vt, __hip_bfloat16* __restrict__ ctx) {
  constexpr int T = 2048, C = 2048, D = 128;
  __shared__ __align__(16) __hip_bfloat16 Ks[64 * 128];    // 16 KB, slot^(row&7)
  __shared__ __align__(16) __hip_bfloat16 Vs[128 * 64];    // 16 KB, slot^(row&7)
  __shared__ __align__(16) __hip_bfloat16 Pl[2][16 * 64];  //  4 KB, slot^c16, m-sequenced
  // total 36864 B -> 4 blocks/CU

  const int tid = threadIdx.x;
  const int w = tid >> 6, lane = tid & 63;
  const int g = lane >> 4, c16 = lane & 15;

  // balanced causal mapping: 2048 blocks; consecutive-4 groups sum qb = 62 (const);
  // 8 heads per XCD for K/V L2 reuse.
  const int bid = blockIdx.x;
  const int x = bid & 7;
  const int i = bid >> 3;                 // 0..255 within XCD
  const int bh = x * 8 + ((i >> 2) & 7);
  const int lo2 = i & 3;
  const int t = i >> 5;                   // 0..7
  const int qb = (lo2 & 1) ? (2 * t + (lo2 >> 1)) : (31 - 2 * t - (lo2 >> 1));
  const int b = bh >> 4, h = bh & 15;
  const int wq = qb * 64 + w * 32;        // wave's 32 q-rows

  const __hip_bfloat16* Qh = Q + (size_t)b * T * C + h * D;
  const __hip_bfloat16* Kh = K + (size_t)b * T * C + h * D;
  const __hip_bfloat16* Vh = Vt + (size_t)bh * D * T;

  const float scale2 = 0.12751744f;       // (1/sqrt(128)) * log2(e)

  short8 qf[2][4];
#pragma unroll
  for (int m = 0; m < 2; ++m)
#pragma unroll
    for (int kk = 0; kk < 4; ++kk) {
      short8 v = *reinterpret_cast<const short8*>(Qh + (size_t)(wq + m * 16 + c16) * C + kk * 32 + g * 8);
      short8 r;
#pragma unroll
      for (int e = 0; e < 8; ++e) {
        unsigned short u = (unsigned short)v[e];
        __hip_bfloat16 bh16 = *reinterpret_cast<__hip_bfloat16*>(&u);
        r[e] = (short)f2bf(__bfloat162float(bh16) * scale2);
      }
      qf[m][kk] = r;
    }

  floatx4 acc[2][8] = {};
  float mrow[2] = {-INFINITY, -INFINITY};
  float lrow[2] = {0.f, 0.f};

  // staging (128 threads): K 8 passes x 8 rows; V 8 passes x 16 rows
  const int kR = tid >> 4;                 // 0..7 row-in-pass
  const int kS = tid & 15;                 // 16B slot (phys computed per row)
  const int vR = tid >> 3;                 // 0..15 row-in-pass
  const int vS = tid & 7;

  short8 kr[8], vr[8];
  auto gloadK = [&](int kb) {
#pragma unroll
    for (int p = 0; p < 8; ++p)
      kr[p] = *reinterpret_cast<const short8*>(Kh + (size_t)(kb + p * 8 + kR) * C + kS * 8);
  };
  auto gloadV = [&](int kb) {
#pragma unroll
    for (int p = 0; p < 8; ++p)
      vr[p] = *reinterpret_cast<const short8*>(Vh + (size_t)(p * 16 + vR) * T + kb + vS * 8);
  };
  auto writeKV = [&]() {
#pragma unroll
    for (int p = 0; p < 8; ++p) {
      const int row = p * 8 + kR;
      *reinterpret_cast<short8*>(&Ks[row * 128 + ((kS ^ (row & 7)) * 8)]) = kr[p];
    }
#pragma unroll
    for (int p = 0; p < 8; ++p) {
      const int row = p * 16 + vR;
      *reinterpret_cast<short8*>(&Vs[row * 64 + ((vS ^ (row & 7)) * 8)]) = vr[p];
    }
  };

  __hip_bfloat16* Pq = Pl[w];
  const int nkt = qb + 1;
  gloadK(0);
  gloadV(0);

  for (int kt = 0; kt < nkt; ++kt) {
    const int kb = kt * 64;
    __syncthreads();                       // prior tile consumed
    writeKV();
    __syncthreads();                       // staged tile visible

    const bool hasnext = (kt + 1 < nkt);
    const bool part = (kb <= wq + 31);
    if (hasnext) gloadK(kb + 64);

    short8 pb[2][2];
    if (part) {
      floatx4 s[2][4] = {};
      __builtin_amdgcn_s_setprio(1);
#pragma unroll
      for (int n = 0; n < 4; ++n)
#pragma unroll
        for (int kk = 0; kk < 4; ++kk) {
          short8 kf = *reinterpret_cast<const short8*>(
              &Ks[(n * 16 + c16) * 128 + (((kk * 4 + g) ^ (c16 & 7)) * 8)]);
          s[0][n] = MFMA16(kf, qf[0][kk], s[0][n]);
          s[1][n] = MFMA16(kf, qf[1][kk], s[1][n]);
        }
      __builtin_amdgcn_s_setprio(0);

      const bool needmask = (kb + 63 > wq);
      float vmax[2];
      if (needmask) {
#pragma unroll
        for (int m = 0; m < 2; ++m) {
          const int q = wq + m * 16 + c16;
          float vm = -INFINITY;
#pragma unroll
          for (int n = 0; n < 4; ++n)
#pragma unroll
            for (int j = 0; j < 4; ++j) {
              float a = s[m][n][j];
              if (kb + n * 16 + g * 4 + j > q) a = -INFINITY;
              s[m][n][j] = a;
              vm = fmaxf(vm, a);
            }
          vmax[m] = vm;
        }
      } else {
#pragma unroll
        for (int m = 0; m < 2; ++m) {
          float v0 = fmaxf(fmaxf(s[m][0][0], s[m][0][1]), fmaxf(s[m][0][2], s[m][0][3]));
          float v1 = fmaxf(fmaxf(s[m][1][0], s[m][1][1]), fmaxf(s[m][1][2], s[m][1][3]));
          float v2 = fmaxf(fmaxf(s[m][2][0], s[m][2][1]), fmaxf(s[m][2][2], s[m][2][3]));
          float v3 = fmaxf(fmaxf(s[m][3][0], s[m][3][1]), fmaxf(s[m][3][2], s[m][3][3]));
          vmax[m] = fmaxf(fmaxf(v0, v1), fmaxf(v2, v3));
        }
      }
#pragma unroll
      for (int m = 0; m < 2; ++m) {
        vmax[m] = fmaxf(vmax[m], __shfl_xor(vmax[m], 16));
        vmax[m] = fmaxf(vmax[m], __shfl_xor(vmax[m], 32));
      }
      const float grow = fmaxf(vmax[0] - mrow[0], vmax[1] - mrow[1]);
      const bool nore = __all(grow <= 8.0f);
#pragma unroll
      for (int m = 0; m < 2; ++m) {
        const float mn = nore ? mrow[m] : fmaxf(mrow[m], vmax[m]);
        float rs = 0.f;
#pragma unroll
        for (int n = 0; n < 4; ++n) {
          float p0 = exp2_fast(s[m][n][0] - mn), p1 = exp2_fast(s[m][n][1] - mn);
          float p2 = exp2_fast(s[m][n][2] - mn), p3 = exp2_fast(s[m][n][3] - mn);
          rs += (p0 + p1) + (p2 + p3);
          ushort4_ pk = { f2bf(p0), f2bf(p1), f2bf(p2), f2bf(p3) };
          *reinterpret_cast<ushort4_*>(&Pq[c16 * 64 + (((4 * n + g) ^ c16) * 4)]) = pk;
        }
        rs += __shfl_xor(rs, 16);
        rs += __shfl_xor(rs, 32);
        if (nore) {
          lrow[m] += rs;
        } else {
          const float sc = exp2_fast(mrow[m] - mn);
          lrow[m] = lrow[m] * sc + rs;
          mrow[m] = mn;
#pragma unroll
          for (int dt = 0; dt < 8; ++dt)
#pragma unroll
            for (int j = 0; j < 4; ++j) acc[m][dt][j] *= sc;
        }
#pragma unroll
        for (int ks = 0; ks < 2; ++ks) {
          short4_ lo3 = *reinterpret_cast<const short4_*>(&Pq[c16 * 64 + (((8 * ks + 2 * g) ^ c16) * 4)]);
          short4_ hi3 = *reinterpret_cast<const short4_*>(&Pq[c16 * 64 + (((8 * ks + 2 * g + 1) ^ c16) * 4)]);
          short8 r;
          r[0] = lo3[0]; r[1] = lo3[1]; r[2] = lo3[2]; r[3] = lo3[3];
          r[4] = hi3[0]; r[5] = hi3[1]; r[6] = hi3[2]; r[7] = hi3[3];
          pb[m][ks] = r;
        }
      }
    }
    if (hasnext) gloadV(kb + 64);
    if (part) {
      __builtin_amdgcn_s_setprio(1);
#pragma unroll
      for (int dt = 0; dt < 8; ++dt)
#pragma unroll
        for (int ks = 0; ks < 2; ++ks) {
          const int pslot = ((ks * 4 + g) ^ (c16 & 7)) * 8;
          short8 vf = *reinterpret_cast<const short8*>(&Vs[(dt * 16 + c16) * 64 + pslot]);
          acc[0][dt] = MFMA16(vf, pb[0][ks], acc[0][dt]);
          acc[1][dt] = MFMA16(vf, pb[1][ks], acc[1][dt]);
        }
      __builtin_amdgcn_s_setprio(0);
    }
  }

#pragma unroll
  for (int m = 0; m < 2; ++m) {
    const float inv = 1.0f / lrow[m];
    const size_t row = (size_t)b * T + wq + m * 16 + c16;
#pragma unroll
    for (int dt = 0; dt < 8; ++dt) {
      ushort4_ o = { f2bf(acc[m][dt][0] * inv), f2bf(acc[m][dt][1] * inv),
                     f2bf(acc[m][dt][2] * inv), f2bf(acc[m][dt][3] * inv) };
      *reinterpret_cast<ushort4_*>(ctx + row * C + h * D + dt * 16 + g * 4) = o;
    }
  }
}

// ---------------------------------------------------------------- launch
extern "C" void kernel_launch(void* const* d_in, const int* in_sizes, int n_in,
                              void* d_out, int out_size, void* d_ws, size_t ws_size,
                              hipStream_t stream) {
  const float* x  = (const float*)d_in[0];
  const float* Wq = (const float*)d_in[1];
  const float* bq = (const float*)d_in[2];
  const float* Wk = (const float*)d_in[3];
  const float* bk = (const float*)d_in[4];
  const float* Wv = (const float*)d_in[5];
  const float* bv = (const float*)d_in[6];
  const float* Wo = (const float*)d_in[7];
  const float* bo = (const float*)d_in[8];

  const int M = 8192, N = 2048, K = 2048;
  const size_t MB = 1u << 20;
  char* ws = (char*)d_ws;
  __hip_bfloat16* xb  = (__hip_bfloat16*)(ws);
  __hip_bfloat16* wqb = (__hip_bfloat16*)(ws + 32 * MB);
  __hip_bfloat16* wkb = (__hip_bfloat16*)(ws + 40 * MB);
  __hip_bfloat16* wvb = (__hip_bfloat16*)(ws + 48 * MB);
  __hip_bfloat16* wob = (__hip_bfloat16*)(ws + 56 * MB);
  __hip_bfloat16* Qb  = (__hip_bfloat16*)(ws + 64 * MB);
  __hip_bfloat16* Kb  = (__hip_bfloat16*)(ws + 96 * MB);
  __hip_bfloat16* Vtb = (__hip_bfloat16*)(ws + 128 * MB);
  if (ws_size < 160 * MB) return;

  cast5_f32_bf16<<<32768, 256, 0, stream>>>(x, Wq, Wk, Wv, Wo, xb, wqb, wkb, wvb, wob);

  const dim3 gg((M / 256) * (N / 256));
  gemm256q<0><<<gg, 512, 0, stream>>>(xb, wqb, bq, Qb, M, N, K);
  gemm256q<0><<<gg, 512, 0, stream>>>(xb, wkb, bk, Kb, M, N, K);
  gemm256q<1><<<gg, 512, 0, stream>>>(xb, wvb, bv, Vtb, M, N, K);

  attn_fwd13<<<64 * 32, 128, 0, stream>>>(Qb, Kb, Vtb, xb);

  gemm256q<2><<<gg, 512, 0, stream>>>(xb, wob, bo, d_out, M, N, K);
}

// Round 20
// 438.581 us; speedup vs baseline: 1.3674x; 1.3674x over previous
//
#include <hip/hip_runtime.h>
#include <hip/hip_bf16.h>
#include <cstdint>
#include <cstddef>

typedef __attribute__((ext_vector_type(8))) short short8;
typedef __attribute__((ext_vector_type(4))) short short4_;
typedef __attribute__((ext_vector_type(4))) float floatx4;
typedef __attribute__((ext_vector_type(4))) unsigned short ushort4_;

#define MFMA16(a, b, c) __builtin_amdgcn_mfma_f32_16x16x32_bf16((a), (b), (c), 0, 0, 0)

__device__ __forceinline__ unsigned short f2bf(float f) {
  __hip_bfloat16 h = __float2bfloat16(f);
  return *reinterpret_cast<unsigned short*>(&h);
}

__device__ __forceinline__ float exp2_fast(float x) {   // bare v_exp_f32 (exp2)
  float r;
  asm("v_exp_f32 %0, %1" : "=v"(r) : "v"(x));
  return r;
}

__device__ __forceinline__ void gl_lds16(const void* g, void* lds) {
  __builtin_amdgcn_global_load_lds(
      (const __attribute__((address_space(1))) void*)g,
      (__attribute__((address_space(3))) void*)lds, 16, 0, 0);
}

// ---------------------------------------------------------------- fused cast kernel
__global__ void cast5_f32_bf16(const float* __restrict__ x, const float* __restrict__ wq,
                               const float* __restrict__ wk, const float* __restrict__ wv,
                               const float* __restrict__ wo,
                               __hip_bfloat16* __restrict__ xb, __hip_bfloat16* __restrict__ wqb,
                               __hip_bfloat16* __restrict__ wkb, __hip_bfloat16* __restrict__ wvb,
                               __hip_bfloat16* __restrict__ wob) {
  const int bid = blockIdx.x;
  const float* src;
  __hip_bfloat16* dst;
  int base;
  if (bid < 16384)      { src = x;  dst = xb;  base = bid; }
  else if (bid < 20480) { src = wq; dst = wqb; base = bid - 16384; }
  else if (bid < 24576) { src = wk; dst = wkb; base = bid - 20480; }
  else if (bid < 28672) { src = wv; dst = wvb; base = bid - 24576; }
  else                  { src = wo; dst = wob; base = bid - 28672; }
  const int i = base * 1024 + threadIdx.x * 4;
  const float4 v = *reinterpret_cast<const float4*>(src + i);
  ushort4_ o = { f2bf(v.x), f2bf(v.y), f2bf(v.z), f2bf(v.w) };
  *reinterpret_cast<ushort4_*>(dst + i) = o;
}

// ---------------------------------------------------------------- GEMM: 256x256, BK=64, 4-phase
// Round-17 proven (~65 us/dispatch, best total 442). UNCHANGED.
template <int MODE>
__global__ __launch_bounds__(512, 2)
void gemm256q(const __hip_bfloat16* __restrict__ Ap, const __hip_bfloat16* __restrict__ Bp,
              const float* __restrict__ bias, void* __restrict__ Cout,
              int M, int N, int K) {
  __shared__ __align__(16) __hip_bfloat16 SA[2][256 * 64];
  __shared__ __align__(16) __hip_bfloat16 SB[2][256 * 64];

  const int tid = threadIdx.x;
  const int wid = tid >> 6, lane = tid & 63;
  const int wr = wid >> 2, wc = wid & 3;
  const int g = lane >> 4, c16 = lane & 15;

  const int nbn = N >> 8;
  const int cpx = gridDim.x >> 3;
  const int swzb = (blockIdx.x & 7) * cpx + (blockIdx.x >> 3);
  const int bm = swzb / nbn, bn = swzb % nbn;

  const int srow8 = lane >> 3;
  const int sc8 = lane & 7;
  const int sgcol = (sc8 ^ srow8) * 8;

  floatx4 acc[8][4] = {};
  short8 af[4], bf[4];

  auto stageA = [&](int p, int kt, int slot) {
    const int ck = p * 8 + wid;
    const int row = ck * 8 + srow8;
    gl_lds16(Ap + (size_t)(bm * 256 + row) * K + kt * 64 + sgcol, SA[slot] + ck * 512);
  };
  auto stageB = [&](int p, int kt, int slot) {
    const int ck = p * 8 + wid;
    const int row = ck * 8 + srow8;
    gl_lds16(Bp + (size_t)(bn * 256 + row) * K + kt * 64 + sgcol, SB[slot] + ck * 512);
  };
  auto readA = [&](int slot, int mh, int kk) {
    const __hip_bfloat16* sa = SA[slot];
#pragma unroll
    for (int mi = 0; mi < 4; ++mi)
      af[mi] = *reinterpret_cast<const short8*>(
          sa + (wr * 128 + (mh * 4 + mi) * 16 + c16) * 64 + (((kk * 4 + g) ^ (c16 & 7)) * 8));
  };
  auto readB = [&](int slot, int kk) {
    const __hip_bfloat16* sb = SB[slot];
#pragma unroll
    for (int n = 0; n < 4; ++n)
      bf[n] = *reinterpret_cast<const short8*>(
          sb + (wc * 64 + n * 16 + c16) * 64 + (((kk * 4 + g) ^ (c16 & 7)) * 8));
  };
  auto mfma_q = [&](int mh) {
    __builtin_amdgcn_s_setprio(1);
#pragma unroll
    for (int mi = 0; mi < 4; ++mi)
#pragma unroll
      for (int n = 0; n < 4; ++n)
        acc[mh * 4 + mi][n] = MFMA16(af[mi], bf[n], acc[mh * 4 + mi][n]);
    __builtin_amdgcn_s_setprio(0);
  };

  const int nkt = K >> 6;
#pragma unroll
  for (int p = 0; p < 4; ++p) { stageA(p, 0, 0); stageB(p, 0, 0); }
  asm volatile("s_waitcnt vmcnt(0)" ::: "memory");
  __builtin_amdgcn_s_barrier();

  for (int kt = 0; kt < nkt; ++kt) {
    const int s = kt & 1;
    const bool hn = (kt + 1 < nkt);
    // phase 0
    readA(s, 0, 0);
    readB(s, 0);
    if (hn) { stageA(0, kt + 1, s ^ 1); stageB(0, kt + 1, s ^ 1);
              stageA(1, kt + 1, s ^ 1); stageB(1, kt + 1, s ^ 1); }
    __builtin_amdgcn_s_barrier();
    mfma_q(0);
    __builtin_amdgcn_s_barrier();
    // phase 1
    readA(s, 1, 0);
    if (hn) { stageA(2, kt + 1, s ^ 1); stageB(2, kt + 1, s ^ 1);
              stageA(3, kt + 1, s ^ 1); stageB(3, kt + 1, s ^ 1); }
    __builtin_amdgcn_s_barrier();
    mfma_q(1);
    __builtin_amdgcn_s_barrier();
    // phase 2
    readA(s, 0, 1);
    readB(s, 1);
    __builtin_amdgcn_s_barrier();
    mfma_q(0);
    __builtin_amdgcn_s_barrier();
    // phase 3
    readA(s, 1, 1);
    __builtin_amdgcn_s_barrier();
    mfma_q(1);
    if (hn) asm volatile("s_waitcnt vmcnt(0)" ::: "memory");
    __builtin_amdgcn_s_barrier();
  }

#pragma unroll
  for (int n = 0; n < 4; ++n) {
    const int colg = bn * 256 + wc * 64 + n * 16 + c16;
    const float bv = bias[colg];
#pragma unroll
    for (int m = 0; m < 8; ++m) {
      const int rowg = bm * 256 + wr * 128 + m * 16 + g * 4;
      if (MODE == 0) {
        __hip_bfloat16* C = (__hip_bfloat16*)Cout;
#pragma unroll
        for (int j = 0; j < 4; ++j)
          C[(size_t)(rowg + j) * N + colg] = __float2bfloat16(acc[m][n][j] + bv);
      } else if (MODE == 1) {
        __hip_bfloat16* C = (__hip_bfloat16*)Cout;
        const int bb = rowg >> 11, t0 = rowg & 2047;
        ushort4_ pk = { f2bf(acc[m][n][0] + bv), f2bf(acc[m][n][1] + bv),
                        f2bf(acc[m][n][2] + bv), f2bf(acc[m][n][3] + bv) };
        *reinterpret_cast<ushort4_*>(C + ((size_t)bb * 2048 + colg) * 2048 + t0) = pk;
      } else {
        float* C = (float*)Cout;
#pragma unroll
        for (int j = 0; j < 4; ++j)
          C[(size_t)(rowg + j) * N + colg] = acc[m][n][j] + bv;
      }
    }
  }
}

// ---------------------------------------------------------------- flash attention v12 (causal)
// Round-16/17 proven: 147 us. UNCHANGED.
__global__ __launch_bounds__(256, 2)
void attn_fwd12(const __hip_bfloat16* __restrict__ Q, const __hip_bfloat16* __restrict__ K,
                const __hip_bfloat16* __restrict__ Vt, __hip_bfloat16* __restrict__ ctx) {
  constexpr int T = 2048, C = 2048, D = 128;
  __shared__ __align__(16) __hip_bfloat16 Ks[64 * 128];
  __shared__ __align__(16) __hip_bfloat16 Vs[128 * 64];
  __shared__ __align__(16) __hip_bfloat16 Pl[4][16 * 64];

  const int tid = threadIdx.x;
  const int w = tid >> 6, lane = tid & 63;
  const int g = lane >> 4, c16 = lane & 15;

  const int bid = blockIdx.x;
  const int x = bid & 7;
  const int i = bid >> 3;
  const int lo = i & 3, hi = i >> 5;
  const int bh = x * 8 + ((i >> 2) & 7);
  const int qb = (int)((0xF12C4A97865B3DE0ull >> (4 * (hi * 4 + lo))) & 15);
  const int b = bh >> 4, h = bh & 15;
  const int wq = qb * 128 + w * 32;

  const __hip_bfloat16* Qh = Q + (size_t)b * T * C + h * D;
  const __hip_bfloat16* Kh = K + (size_t)b * T * C + h * D;
  const __hip_bfloat16* Vh = Vt + (size_t)bh * D * T;

  const float scale2 = 0.12751744f;   // (1/sqrt(128)) * log2(e)

  short8 qf[2][4];
#pragma unroll
  for (int m = 0; m < 2; ++m)
#pragma unroll
    for (int kk = 0; kk < 4; ++kk) {
      short8 v = *reinterpret_cast<const short8*>(Qh + (size_t)(wq + m * 16 + c16) * C + kk * 32 + g * 8);
      short8 r;
#pragma unroll
      for (int e = 0; e < 8; ++e) {
        unsigned short u = (unsigned short)v[e];
        __hip_bfloat16 bh16 = *reinterpret_cast<__hip_bfloat16*>(&u);
        r[e] = (short)f2bf(__bfloat162float(bh16) * scale2);
      }
      qf[m][kk] = r;
    }

  floatx4 acc[2][8] = {};
  float mrow[2] = {-INFINITY, -INFINITY};
  float lrow[2] = {0.f, 0.f};

  const int krow = tid >> 4;
  const int kslot = (tid & 15) ^ (krow & 7);
  const int kgcol = (tid & 15) * 8;
  const int vrow = tid >> 3;
  const int vslot = (tid & 7) ^ (vrow & 7);
  const int vgcol = (tid & 7) * 8;

  short8 kr[4], vr[4];
  auto gloadK = [&](int kb) {
#pragma unroll
    for (int p = 0; p < 4; ++p)
      kr[p] = *reinterpret_cast<const short8*>(Kh + (size_t)(kb + p * 16 + krow) * C + kgcol);
  };
  auto gloadV = [&](int kb) {
#pragma unroll
    for (int p = 0; p < 4; ++p)
      vr[p] = *reinterpret_cast<const short8*>(Vh + (size_t)(p * 32 + vrow) * T + kb + vgcol);
  };

  __hip_bfloat16* Pq = Pl[w];
  const int nkt = qb * 2 + 2;
  gloadK(0);
  gloadV(0);

  for (int kt = 0; kt < nkt; ++kt) {
    const int kb = kt * 64;
    __syncthreads();
#pragma unroll
    for (int p = 0; p < 4; ++p)
      *reinterpret_cast<short8*>(&Ks[(p * 16 + krow) * 128 + kslot * 8]) = kr[p];
#pragma unroll
    for (int p = 0; p < 4; ++p)
      *reinterpret_cast<short8*>(&Vs[(p * 32 + vrow) * 64 + vslot * 8]) = vr[p];
    __syncthreads();

    const bool hasnext = (kt + 1 < nkt);
    const bool part = (kb <= wq + 31);
    if (hasnext) gloadK(kb + 64);

    short8 pb[2][2];
    if (part) {
      floatx4 s[2][4] = {};
      __builtin_amdgcn_s_setprio(1);
#pragma unroll
      for (int n = 0; n < 4; ++n)
#pragma unroll
        for (int kk = 0; kk < 4; ++kk) {
          short8 kf = *reinterpret_cast<const short8*>(
              &Ks[(n * 16 + c16) * 128 + (((kk * 4 + g) ^ (c16 & 7)) * 8)]);
          s[0][n] = MFMA16(kf, qf[0][kk], s[0][n]);
          s[1][n] = MFMA16(kf, qf[1][kk], s[1][n]);
        }
      __builtin_amdgcn_s_setprio(0);

      const bool needmask = (kb + 63 > wq);
      float vmax[2];
      if (needmask) {
#pragma unroll
        for (int m = 0; m < 2; ++m) {
          const int q = wq + m * 16 + c16;
          float vm = -INFINITY;
#pragma unroll
          for (int n = 0; n < 4; ++n)
#pragma unroll
            for (int j = 0; j < 4; ++j) {
              float a = s[m][n][j];
              if (kb + n * 16 + g * 4 + j > q) a = -INFINITY;
              s[m][n][j] = a;
              vm = fmaxf(vm, a);
            }
          vmax[m] = vm;
        }
      } else {
#pragma unroll
        for (int m = 0; m < 2; ++m) {
          float v0 = fmaxf(fmaxf(s[m][0][0], s[m][0][1]), fmaxf(s[m][0][2], s[m][0][3]));
          float v1 = fmaxf(fmaxf(s[m][1][0], s[m][1][1]), fmaxf(s[m][1][2], s[m][1][3]));
          float v2 = fmaxf(fmaxf(s[m][2][0], s[m][2][1]), fmaxf(s[m][2][2], s[m][2][3]));
          float v3 = fmaxf(fmaxf(s[m][3][0], s[m][3][1]), fmaxf(s[m][3][2], s[m][3][3]));
          vmax[m] = fmaxf(fmaxf(v0, v1), fmaxf(v2, v3));
        }
      }
#pragma unroll
      for (int m = 0; m < 2; ++m) {
        vmax[m] = fmaxf(vmax[m], __shfl_xor(vmax[m], 16));
        vmax[m] = fmaxf(vmax[m], __shfl_xor(vmax[m], 32));
      }
      const float grow = fmaxf(vmax[0] - mrow[0], vmax[1] - mrow[1]);
      const bool nore = __all(grow <= 8.0f);
#pragma unroll
      for (int m = 0; m < 2; ++m) {
        const float mn = nore ? mrow[m] : fmaxf(mrow[m], vmax[m]);
        float rs = 0.f;
#pragma unroll
        for (int n = 0; n < 4; ++n) {
          float p0 = exp2_fast(s[m][n][0] - mn), p1 = exp2_fast(s[m][n][1] - mn);
          float p2 = exp2_fast(s[m][n][2] - mn), p3 = exp2_fast(s[m][n][3] - mn);
          rs += (p0 + p1) + (p2 + p3);
          ushort4_ pk = { f2bf(p0), f2bf(p1), f2bf(p2), f2bf(p3) };
          *reinterpret_cast<ushort4_*>(&Pq[c16 * 64 + (((4 * n + g) ^ c16) * 4)]) = pk;
        }
        rs += __shfl_xor(rs, 16);
        rs += __shfl_xor(rs, 32);
        if (nore) {
          lrow[m] += rs;
        } else {
          const float sc = exp2_fast(mrow[m] - mn);
          lrow[m] = lrow[m] * sc + rs;
          mrow[m] = mn;
#pragma unroll
          for (int dt = 0; dt < 8; ++dt)
#pragma unroll
            for (int j = 0; j < 4; ++j) acc[m][dt][j] *= sc;
        }
#pragma unroll
        for (int ks = 0; ks < 2; ++ks) {
          short4_ lo2 = *reinterpret_cast<const short4_*>(&Pq[c16 * 64 + (((8 * ks + 2 * g) ^ c16) * 4)]);
          short4_ hi2 = *reinterpret_cast<const short4_*>(&Pq[c16 * 64 + (((8 * ks + 2 * g + 1) ^ c16) * 4)]);
          short8 r;
          r[0] = lo2[0]; r[1] = lo2[1]; r[2] = lo2[2]; r[3] = lo2[3];
          r[4] = hi2[0]; r[5] = hi2[1]; r[6] = hi2[2]; r[7] = hi2[3];
          pb[m][ks] = r;
        }
      }
    }
    if (hasnext) gloadV(kb + 64);
    if (part) {
      __builtin_amdgcn_s_setprio(1);
#pragma unroll
      for (int dt = 0; dt < 8; ++dt)
#pragma unroll
        for (int ks = 0; ks < 2; ++ks) {
          const int pslot = ((ks * 4 + g) ^ (c16 & 7)) * 8;
          short8 vf = *reinterpret_cast<const short8*>(&Vs[(dt * 16 + c16) * 64 + pslot]);
          acc[0][dt] = MFMA16(vf, pb[0][ks], acc[0][dt]);
          acc[1][dt] = MFMA16(vf, pb[1][ks], acc[1][dt]);
        }
      __builtin_amdgcn_s_setprio(0);
    }
  }

#pragma unroll
  for (int m = 0; m < 2; ++m) {
    const float inv = 1.0f / lrow[m];
    const size_t row = (size_t)b * T + wq + m * 16 + c16;
#pragma unroll
    for (int dt = 0; dt < 8; ++dt) {
      ushort4_ o = { f2bf(acc[m][dt][0] * inv), f2bf(acc[m][dt][1] * inv),
                     f2bf(acc[m][dt][2] * inv), f2bf(acc[m][dt][3] * inv) };
      *reinterpret_cast<ushort4_*>(ctx + row * C + h * D + dt * 16 + g * 4) = o;
    }
  }
}

// ---------------------------------------------------------------- launch
extern "C" void kernel_launch(void* const* d_in, const int* in_sizes, int n_in,
                              void* d_out, int out_size, void* d_ws, size_t ws_size,
                              hipStream_t stream) {
  const float* x  = (const float*)d_in[0];
  const float* Wq = (const float*)d_in[1];
  const float* bq = (const float*)d_in[2];
  const float* Wk = (const float*)d_in[3];
  const float* bk = (const float*)d_in[4];
  const float* Wv = (const float*)d_in[5];
  const float* bv = (const float*)d_in[6];
  const float* Wo = (const float*)d_in[7];
  const float* bo = (const float*)d_in[8];

  const int M = 8192, N = 2048, K = 2048;
  const size_t MB = 1u << 20;
  char* ws = (char*)d_ws;
  __hip_bfloat16* xb  = (__hip_bfloat16*)(ws);
  __hip_bfloat16* wqb = (__hip_bfloat16*)(ws + 32 * MB);
  __hip_bfloat16* wkb = (__hip_bfloat16*)(ws + 40 * MB);
  __hip_bfloat16* wvb = (__hip_bfloat16*)(ws + 48 * MB);
  __hip_bfloat16* wob = (__hip_bfloat16*)(ws + 56 * MB);
  __hip_bfloat16* Qb  = (__hip_bfloat16*)(ws + 64 * MB);
  __hip_bfloat16* Kb  = (__hip_bfloat16*)(ws + 96 * MB);
  __hip_bfloat16* Vtb = (__hip_bfloat16*)(ws + 128 * MB);
  if (ws_size < 160 * MB) return;

  cast5_f32_bf16<<<32768, 256, 0, stream>>>(x, Wq, Wk, Wv, Wo, xb, wqb, wkb, wvb, wob);

  const dim3 gg((M / 256) * (N / 256));
  gemm256q<0><<<gg, 512, 0, stream>>>(xb, wqb, bq, Qb, M, N, K);
  gemm256q<0><<<gg, 512, 0, stream>>>(xb, wkb, bk, Kb, M, N, K);
  gemm256q<1><<<gg, 512, 0, stream>>>(xb, wvb, bv, Vtb, M, N, K);

  attn_fwd12<<<64 * 16, 256, 0, stream>>>(Qb, Kb, Vtb, xb);

  gemm256q<2><<<gg, 512, 0, stream>>>(xb, wob, bo, d_out, M, N, K);
}